// Round 1
// baseline (437.230 us; speedup 1.0000x reference)
//
#include <hip/hip_runtime.h>

// Problem constants (B,S,D fixed by setup_inputs)
#define B_ 16
#define S_ 2048
#define D_ 128
#define SCALE 0.08838834764831845f  // 1/sqrt(128)

typedef __attribute__((ext_vector_type(8))) short short8;   // 8 bf16 (4 VGPRs)
typedef __attribute__((ext_vector_type(4))) float f32x4;    // MFMA C/D

// LDS leading dims (+8 bf16 pad: breaks bank aliasing, keeps 16B row alignment)
#define KQ_LD 136   // feature dim 128 + 8
#define VP_LD 72    // i dim 64 + 8

__device__ __forceinline__ unsigned short f2bf1(float a) {
    union { float f; unsigned u; } x; x.f = a;
    unsigned ua = x.u + 0x7fffu + ((x.u >> 16) & 1u);  // RNE
    return (unsigned short)(ua >> 16);
}
__device__ __forceinline__ unsigned pack2(float a, float b) {
    union { float f; unsigned u; } x, y; x.f = a; y.f = b;
    unsigned ua = x.u + 0x7fffu + ((x.u >> 16) & 1u);
    unsigned ub = y.u + 0x7fffu + ((y.u >> 16) & 1u);
    return (ua >> 16) | (ub & 0xffff0000u);
}

__global__ __launch_bounds__(256, 2)
void attn_kernel(const float* __restrict__ Qg, const float* __restrict__ Kg,
                 const float* __restrict__ Vg, float* __restrict__ out)
{
    __shared__ unsigned short sK[64 * KQ_LD];   // A operand: K rows (the "queries")
    __shared__ unsigned short sQ[64 * KQ_LD];   // B operand: Q rows (the "keys")
    __shared__ unsigned short sV[128 * VP_LD];  // B operand for PV: sV[d][i] (transposed)
    __shared__ unsigned short sP[64 * VP_LD];   // A operand for PV: w in A-layout
    __shared__ float sL[2][64];                 // cross-wave row-sum reduction

    const int tid  = threadIdx.x;
    const int lane = tid & 63;
    const int wv   = tid >> 6;
    const int wr   = wv >> 1;      // wave row (j) half: 0/1
    const int wc   = wv & 1;       // wave col half: 0/1
    const int quad = lane >> 4;
    const int lo   = lane & 15;

    const int b  = blockIdx.x >> 5;
    const int jt = blockIdx.x & 31;   // 64-row j tile index
    const int j0 = jt * 64;

    const float* Qb = Qg + (size_t)b * S_ * D_;
    const float* Kb = Kg + (size_t)b * S_ * D_;
    const float* Vb = Vg + (size_t)b * S_ * D_;
    float* Ob = out + (size_t)b * S_ * D_;
    float* Wb = out + (size_t)B_ * S_ * D_ + (size_t)b * S_ * S_;

    const int rt = tid >> 5;         // 0..7
    const int ct = (tid & 31) * 4;   // 0..124

    // ---- stage K tile (64 x 128 -> bf16) ----
#pragma unroll
    for (int p = 0; p < 8; ++p) {
        const int row = p * 8 + rt;
        const float4 v = *(const float4*)(Kb + (size_t)(j0 + row) * D_ + ct);
        *(uint2*)&sK[row * KQ_LD + ct] = make_uint2(pack2(v.x, v.y), pack2(v.z, v.w));
    }

    // ================= pass 1: row sums l_j = sum_i exp(s) =================
    float lp[2][4] = {{0.f,0.f,0.f,0.f},{0.f,0.f,0.f,0.f}};
    for (int it = jt; it < 32; ++it) {
        __syncthreads();   // prior iter's LDS reads done (also covers sK staging)
#pragma unroll
        for (int p = 0; p < 8; ++p) {
            const int row = p * 8 + rt;
            const float4 v = *(const float4*)(Qb + (size_t)(it * 64 + row) * D_ + ct);
            *(uint2*)&sQ[row * KQ_LD + ct] = make_uint2(pack2(v.x, v.y), pack2(v.z, v.w));
        }
        __syncthreads();

        f32x4 acc[2][2];
#pragma unroll
        for (int r = 0; r < 2; ++r)
#pragma unroll
            for (int c = 0; c < 2; ++c)
                acc[r][c] = (f32x4){0.f, 0.f, 0.f, 0.f};

        const unsigned short* pK = &sK[(wr * 32 + lo) * KQ_LD];
        const unsigned short* pQ = &sQ[(wc * 32 + lo) * KQ_LD];
#pragma unroll
        for (int ks = 0; ks < 4; ++ks) {
            const int ko = ks * 32 + quad * 8;
            short8 a0 = *(const short8*)(pK + ko);
            short8 a1 = *(const short8*)(pK + 16 * KQ_LD + ko);
            short8 b0 = *(const short8*)(pQ + ko);
            short8 b1 = *(const short8*)(pQ + 16 * KQ_LD + ko);
            acc[0][0] = __builtin_amdgcn_mfma_f32_16x16x32_bf16(a0, b0, acc[0][0], 0, 0, 0);
            acc[0][1] = __builtin_amdgcn_mfma_f32_16x16x32_bf16(a0, b1, acc[0][1], 0, 0, 0);
            acc[1][0] = __builtin_amdgcn_mfma_f32_16x16x32_bf16(a1, b0, acc[1][0], 0, 0, 0);
            acc[1][1] = __builtin_amdgcn_mfma_f32_16x16x32_bf16(a1, b1, acc[1][1], 0, 0, 0);
        }

        if (it == jt) {  // diagonal tile: keep i >= j (local compare valid here)
#pragma unroll
            for (int r = 0; r < 2; ++r)
#pragma unroll
                for (int c = 0; c < 2; ++c)
#pragma unroll
                    for (int g = 0; g < 4; ++g) {
                        const int jr = wr * 32 + r * 16 + quad * 4 + g;
                        const int ic = wc * 32 + c * 16 + lo;
                        lp[r][g] += (ic >= jr) ? __expf(acc[r][c][g] * SCALE) : 0.f;
                    }
        } else {
#pragma unroll
            for (int r = 0; r < 2; ++r)
#pragma unroll
                for (int c = 0; c < 2; ++c)
#pragma unroll
                    for (int g = 0; g < 4; ++g)
                        lp[r][g] += __expf(acc[r][c][g] * SCALE);
        }
    }

    // butterfly over the 16 lanes of each quad (cols within this wave's half)
#pragma unroll
    for (int r = 0; r < 2; ++r)
#pragma unroll
        for (int g = 0; g < 4; ++g) {
            float v = lp[r][g];
            v += __shfl_xor(v, 1); v += __shfl_xor(v, 2);
            v += __shfl_xor(v, 4); v += __shfl_xor(v, 8);
            lp[r][g] = v;
        }
    if (lo == 0) {
#pragma unroll
        for (int r = 0; r < 2; ++r)
#pragma unroll
            for (int g = 0; g < 4; ++g)
                sL[wc][wr * 32 + r * 16 + quad * 4 + g] = lp[r][g];
    }
    __syncthreads();
    float rl[2][4];
#pragma unroll
    for (int r = 0; r < 2; ++r)
#pragma unroll
        for (int g = 0; g < 4; ++g) {
            const int row = wr * 32 + r * 16 + quad * 4 + g;
            rl[r][g] = 1.0f / (sL[0][row] + sL[1][row]);
        }

    // ---- zero-fill fully-masked region: cols [0, j0), nontemporal ----
    {
        const f32x4 z = {0.f, 0.f, 0.f, 0.f};
        for (int c0 = tid * 4; c0 < j0; c0 += 1024) {
            float* base = Wb + (size_t)j0 * S_ + c0;
            for (int r = 0; r < 64; ++r) {
                __builtin_nontemporal_store(z, (f32x4*)base);
                base += S_;
            }
        }
    }

    // ================= pass 2: w writes + O = W*V =================
    f32x4 acc_o[2][4];
#pragma unroll
    for (int r = 0; r < 2; ++r)
#pragma unroll
        for (int c = 0; c < 4; ++c)
            acc_o[r][c] = (f32x4){0.f, 0.f, 0.f, 0.f};

    const int dcol = tid & 127;
    const int ih   = (tid >> 7) * 4;

    for (int it = jt; it < 32; ++it) {
        __syncthreads();  // prior iter's sQ/sV/sP reads done
#pragma unroll
        for (int p = 0; p < 8; ++p) {
            const int row = p * 8 + rt;
            const float4 v = *(const float4*)(Qb + (size_t)(it * 64 + row) * D_ + ct);
            *(uint2*)&sQ[row * KQ_LD + ct] = make_uint2(pack2(v.x, v.y), pack2(v.z, v.w));
        }
        // V tile (64 x 128) transposed into sV[d][i]; dword reads stay coalesced
#pragma unroll
        for (int p = 0; p < 8; ++p) {
            const int i0l = p * 8 + ih;
            const float x0 = Vb[(size_t)(it * 64 + i0l + 0) * D_ + dcol];
            const float x1 = Vb[(size_t)(it * 64 + i0l + 1) * D_ + dcol];
            const float x2 = Vb[(size_t)(it * 64 + i0l + 2) * D_ + dcol];
            const float x3 = Vb[(size_t)(it * 64 + i0l + 3) * D_ + dcol];
            *(uint2*)&sV[dcol * VP_LD + i0l] = make_uint2(pack2(x0, x1), pack2(x2, x3));
        }
        __syncthreads();

        f32x4 acc[2][2];
#pragma unroll
        for (int r = 0; r < 2; ++r)
#pragma unroll
            for (int c = 0; c < 2; ++c)
                acc[r][c] = (f32x4){0.f, 0.f, 0.f, 0.f};

        const unsigned short* pK = &sK[(wr * 32 + lo) * KQ_LD];
        const unsigned short* pQ = &sQ[(wc * 32 + lo) * KQ_LD];
#pragma unroll
        for (int ks = 0; ks < 4; ++ks) {
            const int ko = ks * 32 + quad * 8;
            short8 a0 = *(const short8*)(pK + ko);
            short8 a1 = *(const short8*)(pK + 16 * KQ_LD + ko);
            short8 b0 = *(const short8*)(pQ + ko);
            short8 b1 = *(const short8*)(pQ + 16 * KQ_LD + ko);
            acc[0][0] = __builtin_amdgcn_mfma_f32_16x16x32_bf16(a0, b0, acc[0][0], 0, 0, 0);
            acc[0][1] = __builtin_amdgcn_mfma_f32_16x16x32_bf16(a0, b1, acc[0][1], 0, 0, 0);
            acc[1][0] = __builtin_amdgcn_mfma_f32_16x16x32_bf16(a1, b0, acc[1][0], 0, 0, 0);
            acc[1][1] = __builtin_amdgcn_mfma_f32_16x16x32_bf16(a1, b1, acc[1][1], 0, 0, 0);
        }

        if (it == jt) {
#pragma unroll
            for (int r = 0; r < 2; ++r)
#pragma unroll
                for (int c = 0; c < 2; ++c)
#pragma unroll
                    for (int g = 0; g < 4; ++g) {
                        const int jr = wr * 32 + r * 16 + quad * 4 + g;
                        const int ic = wc * 32 + c * 16 + lo;
                        const float p = (ic >= jr) ? __expf(acc[r][c][g] * SCALE) : 0.f;
                        const float w = p * rl[r][g];
                        __builtin_nontemporal_store(
                            w, Wb + (size_t)(j0 + jr) * S_ + (size_t)(it * 64 + ic));
                        sP[jr * VP_LD + ic] = f2bf1(w);
                    }
        } else {
#pragma unroll
            for (int r = 0; r < 2; ++r)
#pragma unroll
                for (int c = 0; c < 2; ++c)
#pragma unroll
                    for (int g = 0; g < 4; ++g) {
                        const int jr = wr * 32 + r * 16 + quad * 4 + g;
                        const int ic = wc * 32 + c * 16 + lo;
                        const float w = __expf(acc[r][c][g] * SCALE) * rl[r][g];
                        __builtin_nontemporal_store(
                            w, Wb + (size_t)(j0 + jr) * S_ + (size_t)(it * 64 + ic));
                        sP[jr * VP_LD + ic] = f2bf1(w);
                    }
        }
        __syncthreads();  // sP visible to all waves

        // O += W(64 x 64) * V(64 x 128); wave does 32(j) x 64(d)
        const unsigned short* pP = &sP[(wr * 32 + lo) * VP_LD];
        const unsigned short* pV = &sV[(wc * 64 + lo) * VP_LD];
#pragma unroll
        for (int ks = 0; ks < 2; ++ks) {
            const int ko = ks * 32 + quad * 8;
            short8 a0 = *(const short8*)(pP + ko);
            short8 a1 = *(const short8*)(pP + 16 * VP_LD + ko);
#pragma unroll
            for (int c2 = 0; c2 < 4; ++c2) {
                short8 bv = *(const short8*)(pV + c2 * 16 * VP_LD + ko);
                acc_o[0][c2] = __builtin_amdgcn_mfma_f32_16x16x32_bf16(a0, bv, acc_o[0][c2], 0, 0, 0);
                acc_o[1][c2] = __builtin_amdgcn_mfma_f32_16x16x32_bf16(a1, bv, acc_o[1][c2], 0, 0, 0);
            }
        }
    }

    // ---- write outputs O (64 x 128 fp32) ----
#pragma unroll
    for (int r = 0; r < 2; ++r)
#pragma unroll
        for (int c2 = 0; c2 < 4; ++c2)
#pragma unroll
            for (int g = 0; g < 4; ++g) {
                const int jr = wr * 32 + r * 16 + quad * 4 + g;
                const int dc = wc * 64 + c2 * 16 + lo;
                Ob[(size_t)(j0 + jr) * D_ + dc] = acc_o[r][c2][g];
            }
}

extern "C" void kernel_launch(void* const* d_in, const int* in_sizes, int n_in,
                              void* d_out, int out_size, void* d_ws, size_t ws_size,
                              hipStream_t stream) {
    const float* Q = (const float*)d_in[0];
    const float* K = (const float*)d_in[1];
    const float* V = (const float*)d_in[2];
    float* out = (float*)d_out;
    (void)in_sizes; (void)n_in; (void)out_size; (void)d_ws; (void)ws_size;
    hipLaunchKernelGGL(attn_kernel, dim3(16 * 32), dim3(256), 0, stream, Q, K, V, out);
}

// Round 2
// 410.616 us; speedup vs baseline: 1.0648x; 1.0648x over previous
//
#include <hip/hip_runtime.h>

// Problem constants (B,S,D fixed by setup_inputs)
#define B_ 16
#define S_ 2048
#define D_ 128
#define SCALE 0.08838834764831845f  // 1/sqrt(128)

typedef __attribute__((ext_vector_type(8))) short short8;   // 8 bf16 (4 VGPRs)
typedef __attribute__((ext_vector_type(4))) short short4v;  // 4 bf16 (2 VGPRs)
typedef __attribute__((ext_vector_type(4))) float f32x4;    // MFMA C/D

// LDS leading dims
#define KQ_LD 136   // 128 + 8 (16B-aligned rows, bank stride 68%32=4)
#define VP_LD 68    // 64 + 4  (8B-aligned rows, bank stride 34%32=2 -> 4-way max)
#define PP_LD 72    // 64 + 8  (16B-aligned rows for b128 A-frag reads)

__device__ __forceinline__ unsigned short f2bf1(float a) {
    union { float f; unsigned u; } x; x.f = a;
    unsigned ua = x.u + 0x7fffu + ((x.u >> 16) & 1u);  // RNE
    return (unsigned short)(ua >> 16);
}
__device__ __forceinline__ unsigned pack2(float a, float b) {
    union { float f; unsigned u; } x, y; x.f = a; y.f = b;
    unsigned ua = x.u + 0x7fffu + ((x.u >> 16) & 1u);
    unsigned ub = y.u + 0x7fffu + ((y.u >> 16) & 1u);
    return (ua >> 16) | (ub & 0xffff0000u);
}
__device__ __forceinline__ short8 ldsV8(const unsigned short* p) {
    short4v a = *(const short4v*)p;
    short4v b = *(const short4v*)(p + 4);
    return __builtin_shufflevector(a, b, 0, 1, 2, 3, 4, 5, 6, 7);
}

__global__ __launch_bounds__(256, 2)
void attn_kernel(const float* __restrict__ Qg, const float* __restrict__ Kg,
                 const float* __restrict__ Vg, float* __restrict__ out)
{
    __shared__ unsigned short sK[64 * KQ_LD];   // A operand: K rows (the "queries")
    __shared__ unsigned short sQ[64 * KQ_LD];   // B operand: Q rows (the "keys")
    __shared__ unsigned short sV[128 * VP_LD];  // B operand for PV: sV[d][i]
    __shared__ unsigned short sP[64 * PP_LD];   // A operand for PV: w in A-layout
    __shared__ float sL[2][64];                 // cross-wave row-sum reduction

    const int tid  = threadIdx.x;
    const int lane = tid & 63;
    const int wv   = tid >> 6;
    const int wr   = wv >> 1;      // wave row (j) half: 0/1
    const int wc   = wv & 1;       // wave col half: 0/1
    const int quad = lane >> 4;
    const int lo   = lane & 15;

    // complement pairing: blocks p and p+256 get jt and 31-jt of the same b,
    // so the two co-resident blocks on a CU total exactly 33 tile-iters.
    const int half = blockIdx.x >> 8;
    const int p_   = blockIdx.x & 255;
    const int b    = p_ >> 4;
    const int jq   = p_ & 15;
    const int jt   = half ? (31 - jq) : jq;
    const int j0   = jt * 64;

    const float* Qb = Qg + (size_t)b * S_ * D_;
    const float* Kb = Kg + (size_t)b * S_ * D_;
    const float* Vb = Vg + (size_t)b * S_ * D_;
    float* Ob = out + (size_t)b * S_ * D_;
    float* Wb = out + (size_t)B_ * S_ * D_ + (size_t)b * S_ * S_;

    const int rt = tid >> 5;         // 0..7
    const int ct = (tid & 31) * 4;   // 0..124

    // ---- stage K tile (64 x 128 -> bf16) ----
#pragma unroll
    for (int p = 0; p < 8; ++p) {
        const int row = p * 8 + rt;
        const float4 v = *(const float4*)(Kb + (size_t)(j0 + row) * D_ + ct);
        *(uint2*)&sK[row * KQ_LD + ct] = make_uint2(pack2(v.x, v.y), pack2(v.z, v.w));
    }

    // ================= pass 1: row sums l_j = sum_i exp(s) =================
    float lp[2][4] = {{0.f,0.f,0.f,0.f},{0.f,0.f,0.f,0.f}};
    float4 qpre[8];
#pragma unroll
    for (int p = 0; p < 8; ++p)
        qpre[p] = *(const float4*)(Qb + (size_t)(jt * 64 + p * 8 + rt) * D_ + ct);

    for (int it = jt; it < 32; ++it) {
        __syncthreads();   // prior iter's sQ reads done (also covers sK staging)
#pragma unroll
        for (int p = 0; p < 8; ++p) {
            const float4 v = qpre[p];
            *(uint2*)&sQ[(p * 8 + rt) * KQ_LD + ct] =
                make_uint2(pack2(v.x, v.y), pack2(v.z, v.w));
        }
        __syncthreads();
        if (it + 1 < 32) {   // prefetch next Q tile; latency hides behind MFMA+exp
#pragma unroll
            for (int p = 0; p < 8; ++p)
                qpre[p] = *(const float4*)(Qb + (size_t)((it + 1) * 64 + p * 8 + rt) * D_ + ct);
        }

        f32x4 acc[2][2];
#pragma unroll
        for (int r = 0; r < 2; ++r)
#pragma unroll
            for (int c = 0; c < 2; ++c)
                acc[r][c] = (f32x4){0.f, 0.f, 0.f, 0.f};

        const unsigned short* pK = &sK[(wr * 32 + lo) * KQ_LD];
        const unsigned short* pQ = &sQ[(wc * 32 + lo) * KQ_LD];
#pragma unroll
        for (int ks = 0; ks < 4; ++ks) {
            const int ko = ks * 32 + quad * 8;
            short8 a0 = *(const short8*)(pK + ko);
            short8 a1 = *(const short8*)(pK + 16 * KQ_LD + ko);
            short8 b0 = *(const short8*)(pQ + ko);
            short8 b1 = *(const short8*)(pQ + 16 * KQ_LD + ko);
            acc[0][0] = __builtin_amdgcn_mfma_f32_16x16x32_bf16(a0, b0, acc[0][0], 0, 0, 0);
            acc[0][1] = __builtin_amdgcn_mfma_f32_16x16x32_bf16(a0, b1, acc[0][1], 0, 0, 0);
            acc[1][0] = __builtin_amdgcn_mfma_f32_16x16x32_bf16(a1, b0, acc[1][0], 0, 0, 0);
            acc[1][1] = __builtin_amdgcn_mfma_f32_16x16x32_bf16(a1, b1, acc[1][1], 0, 0, 0);
        }

        if (it == jt) {  // diagonal tile: keep i >= j
#pragma unroll
            for (int r = 0; r < 2; ++r)
#pragma unroll
                for (int c = 0; c < 2; ++c)
#pragma unroll
                    for (int g = 0; g < 4; ++g) {
                        const int jr = wr * 32 + r * 16 + quad * 4 + g;
                        const int ic = wc * 32 + c * 16 + lo;
                        lp[r][g] += (ic >= jr) ? __expf(acc[r][c][g] * SCALE) : 0.f;
                    }
        } else {
#pragma unroll
            for (int r = 0; r < 2; ++r)
#pragma unroll
                for (int c = 0; c < 2; ++c)
#pragma unroll
                    for (int g = 0; g < 4; ++g)
                        lp[r][g] += __expf(acc[r][c][g] * SCALE);
        }
    }

    // butterfly over the 16 lanes of each quad
#pragma unroll
    for (int r = 0; r < 2; ++r)
#pragma unroll
        for (int g = 0; g < 4; ++g) {
            float v = lp[r][g];
            v += __shfl_xor(v, 1); v += __shfl_xor(v, 2);
            v += __shfl_xor(v, 4); v += __shfl_xor(v, 8);
            lp[r][g] = v;
        }
    if (lo == 0) {
#pragma unroll
        for (int r = 0; r < 2; ++r)
#pragma unroll
            for (int g = 0; g < 4; ++g)
                sL[wc][wr * 32 + r * 16 + quad * 4 + g] = lp[r][g];
    }
    __syncthreads();
    float rl[2][4];
#pragma unroll
    for (int r = 0; r < 2; ++r)
#pragma unroll
        for (int g = 0; g < 4; ++g) {
            const int row = wr * 32 + r * 16 + quad * 4 + g;
            rl[r][g] = 1.0f / (sL[0][row] + sL[1][row]);
        }

    // ---- zero-fill fully-masked region: cols [0, j0), nontemporal ----
    {
        const f32x4 z = {0.f, 0.f, 0.f, 0.f};
        for (int c0 = tid * 4; c0 < j0; c0 += 1024) {
            float* base = Wb + (size_t)j0 * S_ + c0;
            for (int r = 0; r < 64; ++r) {
                __builtin_nontemporal_store(z, (f32x4*)base);
                base += S_;
            }
        }
    }

    // ================= pass 2: w writes + O = W*V =================
    f32x4 acc_o[2][4];
#pragma unroll
    for (int r = 0; r < 2; ++r)
#pragma unroll
        for (int c = 0; c < 4; ++c)
            acc_o[r][c] = (f32x4){0.f, 0.f, 0.f, 0.f};

    const int dcol = tid & 127;
    const int ih   = (tid >> 7) * 4;

    float vpre[8][4];
#pragma unroll
    for (int p = 0; p < 8; ++p) {
        const int i0l = p * 8 + ih;
#pragma unroll
        for (int q = 0; q < 4; ++q)
            vpre[p][q] = Vb[(size_t)(jt * 64 + i0l + q) * D_ + dcol];
    }
#pragma unroll
    for (int p = 0; p < 8; ++p)
        qpre[p] = *(const float4*)(Qb + (size_t)(jt * 64 + p * 8 + rt) * D_ + ct);

    for (int it = jt; it < 32; ++it) {
        __syncthreads();  // prior iter's sQ/sV/sP reads done (first: sL reads done)
#pragma unroll
        for (int p = 0; p < 8; ++p) {
            const float4 v = qpre[p];
            *(uint2*)&sQ[(p * 8 + rt) * KQ_LD + ct] =
                make_uint2(pack2(v.x, v.y), pack2(v.z, v.w));
        }
#pragma unroll
        for (int p = 0; p < 8; ++p) {
            const int i0l = p * 8 + ih;
            *(uint2*)&sV[dcol * VP_LD + i0l] =
                make_uint2(pack2(vpre[p][0], vpre[p][1]), pack2(vpre[p][2], vpre[p][3]));
        }
        __syncthreads();

        if (it + 1 < 32) {  // prefetch next Q and V tiles
#pragma unroll
            for (int p = 0; p < 8; ++p)
                qpre[p] = *(const float4*)(Qb + (size_t)((it + 1) * 64 + p * 8 + rt) * D_ + ct);
#pragma unroll
            for (int p = 0; p < 8; ++p) {
                const int i0l = p * 8 + ih;
#pragma unroll
                for (int q = 0; q < 4; ++q)
                    vpre[p][q] = Vb[(size_t)((it + 1) * 64 + i0l + q) * D_ + dcol];
            }
        }

        f32x4 acc[2][2];
#pragma unroll
        for (int r = 0; r < 2; ++r)
#pragma unroll
            for (int c = 0; c < 2; ++c)
                acc[r][c] = (f32x4){0.f, 0.f, 0.f, 0.f};

        const unsigned short* pK = &sK[(wr * 32 + lo) * KQ_LD];
        const unsigned short* pQ = &sQ[(wc * 32 + lo) * KQ_LD];
#pragma unroll
        for (int ks = 0; ks < 4; ++ks) {
            const int ko = ks * 32 + quad * 8;
            short8 a0 = *(const short8*)(pK + ko);
            short8 a1 = *(const short8*)(pK + 16 * KQ_LD + ko);
            short8 b0 = *(const short8*)(pQ + ko);
            short8 b1 = *(const short8*)(pQ + 16 * KQ_LD + ko);
            acc[0][0] = __builtin_amdgcn_mfma_f32_16x16x32_bf16(a0, b0, acc[0][0], 0, 0, 0);
            acc[0][1] = __builtin_amdgcn_mfma_f32_16x16x32_bf16(a0, b1, acc[0][1], 0, 0, 0);
            acc[1][0] = __builtin_amdgcn_mfma_f32_16x16x32_bf16(a1, b0, acc[1][0], 0, 0, 0);
            acc[1][1] = __builtin_amdgcn_mfma_f32_16x16x32_bf16(a1, b1, acc[1][1], 0, 0, 0);
        }

        if (it == jt) {
#pragma unroll
            for (int r = 0; r < 2; ++r)
#pragma unroll
                for (int c = 0; c < 2; ++c)
#pragma unroll
                    for (int g = 0; g < 4; ++g) {
                        const int jr = wr * 32 + r * 16 + quad * 4 + g;
                        const int ic = wc * 32 + c * 16 + lo;
                        const float pw = (ic >= jr) ? __expf(acc[r][c][g] * SCALE) : 0.f;
                        const float w = pw * rl[r][g];
                        __builtin_nontemporal_store(
                            w, Wb + (size_t)(j0 + jr) * S_ + (size_t)(it * 64 + ic));
                        sP[jr * PP_LD + ic] = f2bf1(w);
                    }
        } else {
#pragma unroll
            for (int r = 0; r < 2; ++r)
#pragma unroll
                for (int c = 0; c < 2; ++c)
#pragma unroll
                    for (int g = 0; g < 4; ++g) {
                        const int jr = wr * 32 + r * 16 + quad * 4 + g;
                        const int ic = wc * 32 + c * 16 + lo;
                        const float w = __expf(acc[r][c][g] * SCALE) * rl[r][g];
                        __builtin_nontemporal_store(
                            w, Wb + (size_t)(j0 + jr) * S_ + (size_t)(it * 64 + ic));
                        sP[jr * PP_LD + ic] = f2bf1(w);
                    }
        }
        __syncthreads();  // sP visible to all waves

        // O += W(64 x 64) * V(64 x 128); wave does 32(j) x 64(d)
        const unsigned short* pP = &sP[(wr * 32 + lo) * PP_LD];
        const unsigned short* pV = &sV[(wc * 64 + lo) * VP_LD];
#pragma unroll
        for (int ks = 0; ks < 2; ++ks) {
            const int ko = ks * 32 + quad * 8;
            short8 a0 = *(const short8*)(pP + ko);
            short8 a1 = *(const short8*)(pP + 16 * PP_LD + ko);
#pragma unroll
            for (int c2 = 0; c2 < 4; ++c2) {
                short8 bv = ldsV8(pV + c2 * 16 * VP_LD + ko);
                acc_o[0][c2] = __builtin_amdgcn_mfma_f32_16x16x32_bf16(a0, bv, acc_o[0][c2], 0, 0, 0);
                acc_o[1][c2] = __builtin_amdgcn_mfma_f32_16x16x32_bf16(a1, bv, acc_o[1][c2], 0, 0, 0);
            }
        }
    }

    // ---- write outputs O (64 x 128 fp32) ----
#pragma unroll
    for (int r = 0; r < 2; ++r)
#pragma unroll
        for (int c2 = 0; c2 < 4; ++c2)
#pragma unroll
            for (int g = 0; g < 4; ++g) {
                const int jr = wr * 32 + r * 16 + quad * 4 + g;
                const int dc = wc * 64 + c2 * 16 + lo;
                Ob[(size_t)(j0 + jr) * D_ + dc] = acc_o[r][c2][g];
            }
}

extern "C" void kernel_launch(void* const* d_in, const int* in_sizes, int n_in,
                              void* d_out, int out_size, void* d_ws, size_t ws_size,
                              hipStream_t stream) {
    const float* Q = (const float*)d_in[0];
    const float* K = (const float*)d_in[1];
    const float* V = (const float*)d_in[2];
    float* out = (float*)d_out;
    (void)in_sizes; (void)n_in; (void)out_size; (void)d_ws; (void)ws_size;
    hipLaunchKernelGGL(attn_kernel, dim3(16 * 32), dim3(256), 0, stream, Q, K, V, out);
}

// Round 3
// 370.056 us; speedup vs baseline: 1.1815x; 1.1096x over previous
//
#include <hip/hip_runtime.h>

// Problem constants (B,S,D fixed by setup_inputs)
#define B_ 16
#define S_ 2048
#define D_ 128
#define SCALE 0.08838834764831845f  // 1/sqrt(128)

typedef __attribute__((ext_vector_type(8))) short short8;   // 8 bf16 (4 VGPRs)
typedef __attribute__((ext_vector_type(4))) short short4v;  // 4 bf16 (2 VGPRs)
typedef __attribute__((ext_vector_type(4))) float f32x4;    // MFMA C/D

// LDS leading dims
#define KQ_LD 136   // 128 + 8 (16B-aligned rows, bank stride 68%32=4)
#define VP_LD 68    // 64 + 4  (8B-aligned rows, bank stride 34%32=2 -> 4-way max)
#define PP_LD 72    // 64 + 8  (16B-aligned rows for b128 A-frag reads)

__device__ __forceinline__ unsigned short f2bf1(float a) {
    union { float f; unsigned u; } x; x.f = a;
    unsigned ua = x.u + 0x7fffu + ((x.u >> 16) & 1u);  // RNE
    return (unsigned short)(ua >> 16);
}
__device__ __forceinline__ unsigned pack2(float a, float b) {
    union { float f; unsigned u; } x, y; x.f = a; y.f = b;
    unsigned ua = x.u + 0x7fffu + ((x.u >> 16) & 1u);
    unsigned ub = y.u + 0x7fffu + ((y.u >> 16) & 1u);
    return (ua >> 16) | (ub & 0xffff0000u);
}
__device__ __forceinline__ short8 ldsV8(const unsigned short* p) {
    short4v a = *(const short4v*)p;
    short4v b = *(const short4v*)(p + 4);
    return __builtin_shufflevector(a, b, 0, 1, 2, 3, 4, 5, 6, 7);
}

__global__ __launch_bounds__(256, 2)
void attn_kernel(const float* __restrict__ Qg, const float* __restrict__ Kg,
                 const float* __restrict__ Vg, float* __restrict__ out)
{
    __shared__ unsigned short sK[64 * KQ_LD];   // A operand: K rows (the "queries")
    __shared__ unsigned short sQ[64 * KQ_LD];   // B operand: Q rows (the "keys")
    __shared__ unsigned short sV[128 * VP_LD];  // B operand for PV: sV[d][i]
    __shared__ unsigned short sP[64 * PP_LD];   // A operand for PV: w in A-layout
    __shared__ float sL[2][64];                 // cross-wave row-sum reduction

    const int tid  = threadIdx.x;
    const int lane = tid & 63;
    const int wv   = tid >> 6;
    const int wr   = wv >> 1;      // wave row (j) half: 0/1
    const int wc   = wv & 1;       // wave col half: 0/1
    const int quad = lane >> 4;
    const int lo   = lane & 15;

    // XCD-aware mapping (blockIdx%8 -> XCD round-robin heuristic):
    //   XCD x owns batches {2x, 2x+1}; all 32 j-tiles of a batch share that
    //   XCD's L2, so Q/V re-reads (the round-2 400MB FETCH) become L2 hits.
    //   CU slot k pairs jt=k (batch 2x) with jt=31-k (batch 2x+1): balanced 33.
    const int x     = blockIdx.x & 7;    // XCD
    const int k     = blockIdx.x >> 3;   // dispatch order within XCD: 0..63
    const int slot  = k & 31;            // CU within XCD (first/second fill)
    const int wave2 = k >> 5;            // 0 = first occupancy slot, 1 = second
    const int b     = 2 * x + wave2;
    const int jt    = wave2 ? (31 - slot) : slot;
    const int j0    = jt * 64;

    const float* Qb = Qg + (size_t)b * S_ * D_;
    const float* Kb = Kg + (size_t)b * S_ * D_;
    const float* Vb = Vg + (size_t)b * S_ * D_;
    float* Ob = out + (size_t)b * S_ * D_;
    float* Wb = out + (size_t)B_ * S_ * D_ + (size_t)b * S_ * S_;

    const int rt = tid >> 5;         // 0..7
    const int ct = (tid & 31) * 4;   // 0..124

    // ---- stage K tile (64 x 128 -> bf16) ----
#pragma unroll
    for (int p = 0; p < 8; ++p) {
        const int row = p * 8 + rt;
        const float4 v = *(const float4*)(Kb + (size_t)(j0 + row) * D_ + ct);
        *(uint2*)&sK[row * KQ_LD + ct] = make_uint2(pack2(v.x, v.y), pack2(v.z, v.w));
    }

    // ================= pass 1: row sums l_j = sum_i exp(s) =================
    float lp[2][4] = {{0.f,0.f,0.f,0.f},{0.f,0.f,0.f,0.f}};
    float4 qpre[8];
#pragma unroll
    for (int p = 0; p < 8; ++p)
        qpre[p] = *(const float4*)(Qb + (size_t)(jt * 64 + p * 8 + rt) * D_ + ct);

    for (int it = jt; it < 32; ++it) {
        __syncthreads();   // prior iter's sQ reads done (also covers sK staging)
#pragma unroll
        for (int p = 0; p < 8; ++p) {
            const float4 v = qpre[p];
            *(uint2*)&sQ[(p * 8 + rt) * KQ_LD + ct] =
                make_uint2(pack2(v.x, v.y), pack2(v.z, v.w));
        }
        __syncthreads();
        if (it + 1 < 32) {   // prefetch next Q tile; latency hides behind MFMA+exp
#pragma unroll
            for (int p = 0; p < 8; ++p)
                qpre[p] = *(const float4*)(Qb + (size_t)((it + 1) * 64 + p * 8 + rt) * D_ + ct);
        }

        f32x4 acc[2][2];
#pragma unroll
        for (int r = 0; r < 2; ++r)
#pragma unroll
            for (int c = 0; c < 2; ++c)
                acc[r][c] = (f32x4){0.f, 0.f, 0.f, 0.f};

        const unsigned short* pK = &sK[(wr * 32 + lo) * KQ_LD];
        const unsigned short* pQ = &sQ[(wc * 32 + lo) * KQ_LD];
#pragma unroll
        for (int ks = 0; ks < 4; ++ks) {
            const int ko = ks * 32 + quad * 8;
            short8 a0 = *(const short8*)(pK + ko);
            short8 a1 = *(const short8*)(pK + 16 * KQ_LD + ko);
            short8 b0 = *(const short8*)(pQ + ko);
            short8 b1 = *(const short8*)(pQ + 16 * KQ_LD + ko);
            acc[0][0] = __builtin_amdgcn_mfma_f32_16x16x32_bf16(a0, b0, acc[0][0], 0, 0, 0);
            acc[0][1] = __builtin_amdgcn_mfma_f32_16x16x32_bf16(a0, b1, acc[0][1], 0, 0, 0);
            acc[1][0] = __builtin_amdgcn_mfma_f32_16x16x32_bf16(a1, b0, acc[1][0], 0, 0, 0);
            acc[1][1] = __builtin_amdgcn_mfma_f32_16x16x32_bf16(a1, b1, acc[1][1], 0, 0, 0);
        }

        if (it == jt) {  // diagonal tile: keep i >= j
#pragma unroll
            for (int r = 0; r < 2; ++r)
#pragma unroll
                for (int c = 0; c < 2; ++c)
#pragma unroll
                    for (int g = 0; g < 4; ++g) {
                        const int jr = wr * 32 + r * 16 + quad * 4 + g;
                        const int ic = wc * 32 + c * 16 + lo;
                        lp[r][g] += (ic >= jr) ? __expf(acc[r][c][g] * SCALE) : 0.f;
                    }
        } else {
#pragma unroll
            for (int r = 0; r < 2; ++r)
#pragma unroll
                for (int c = 0; c < 2; ++c)
#pragma unroll
                    for (int g = 0; g < 4; ++g)
                        lp[r][g] += __expf(acc[r][c][g] * SCALE);
        }
    }

    // butterfly over the 16 lanes of each quad
#pragma unroll
    for (int r = 0; r < 2; ++r)
#pragma unroll
        for (int g = 0; g < 4; ++g) {
            float v = lp[r][g];
            v += __shfl_xor(v, 1); v += __shfl_xor(v, 2);
            v += __shfl_xor(v, 4); v += __shfl_xor(v, 8);
            lp[r][g] = v;
        }
    if (lo == 0) {
#pragma unroll
        for (int r = 0; r < 2; ++r)
#pragma unroll
            for (int g = 0; g < 4; ++g)
                sL[wc][wr * 32 + r * 16 + quad * 4 + g] = lp[r][g];
    }
    __syncthreads();
    float rl[2][4];
#pragma unroll
    for (int r = 0; r < 2; ++r)
#pragma unroll
        for (int g = 0; g < 4; ++g) {
            const int row = wr * 32 + r * 16 + quad * 4 + g;
            rl[r][g] = 1.0f / (sL[0][row] + sL[1][row]);
        }

    // ---- zero-fill fully-masked region: cols [0, j0), nontemporal ----
    {
        const f32x4 z = {0.f, 0.f, 0.f, 0.f};
        for (int c0 = tid * 4; c0 < j0; c0 += 1024) {
            float* base = Wb + (size_t)j0 * S_ + c0;
            for (int r = 0; r < 64; ++r) {
                __builtin_nontemporal_store(z, (f32x4*)base);
                base += S_;
            }
        }
    }

    // ================= pass 2: w writes + O = W*V =================
    f32x4 acc_o[2][4];
#pragma unroll
    for (int r = 0; r < 2; ++r)
#pragma unroll
        for (int c = 0; c < 4; ++c)
            acc_o[r][c] = (f32x4){0.f, 0.f, 0.f, 0.f};

    const int dcol = tid & 127;
    const int ih   = (tid >> 7) * 4;

    float vpre[8][4];
#pragma unroll
    for (int p = 0; p < 8; ++p) {
        const int i0l = p * 8 + ih;
#pragma unroll
        for (int q = 0; q < 4; ++q)
            vpre[p][q] = Vb[(size_t)(jt * 64 + i0l + q) * D_ + dcol];
    }
#pragma unroll
    for (int p = 0; p < 8; ++p)
        qpre[p] = *(const float4*)(Qb + (size_t)(jt * 64 + p * 8 + rt) * D_ + ct);

    for (int it = jt; it < 32; ++it) {
        __syncthreads();  // prior iter's sQ/sV/sP reads done (first: sL reads done)
#pragma unroll
        for (int p = 0; p < 8; ++p) {
            const float4 v = qpre[p];
            *(uint2*)&sQ[(p * 8 + rt) * KQ_LD + ct] =
                make_uint2(pack2(v.x, v.y), pack2(v.z, v.w));
        }
#pragma unroll
        for (int p = 0; p < 8; ++p) {
            const int i0l = p * 8 + ih;
            *(uint2*)&sV[dcol * VP_LD + i0l] =
                make_uint2(pack2(vpre[p][0], vpre[p][1]), pack2(vpre[p][2], vpre[p][3]));
        }
        __syncthreads();

        if (it + 1 < 32) {  // prefetch next Q and V tiles
#pragma unroll
            for (int p = 0; p < 8; ++p)
                qpre[p] = *(const float4*)(Qb + (size_t)((it + 1) * 64 + p * 8 + rt) * D_ + ct);
#pragma unroll
            for (int p = 0; p < 8; ++p) {
                const int i0l = p * 8 + ih;
#pragma unroll
                for (int q = 0; q < 4; ++q)
                    vpre[p][q] = Vb[(size_t)((it + 1) * 64 + i0l + q) * D_ + dcol];
            }
        }

        f32x4 acc[2][2];
#pragma unroll
        for (int r = 0; r < 2; ++r)
#pragma unroll
            for (int c = 0; c < 2; ++c)
                acc[r][c] = (f32x4){0.f, 0.f, 0.f, 0.f};

        const unsigned short* pK = &sK[(wr * 32 + lo) * KQ_LD];
        const unsigned short* pQ = &sQ[(wc * 32 + lo) * KQ_LD];
#pragma unroll
        for (int ks = 0; ks < 4; ++ks) {
            const int ko = ks * 32 + quad * 8;
            short8 a0 = *(const short8*)(pK + ko);
            short8 a1 = *(const short8*)(pK + 16 * KQ_LD + ko);
            short8 b0 = *(const short8*)(pQ + ko);
            short8 b1 = *(const short8*)(pQ + 16 * KQ_LD + ko);
            acc[0][0] = __builtin_amdgcn_mfma_f32_16x16x32_bf16(a0, b0, acc[0][0], 0, 0, 0);
            acc[0][1] = __builtin_amdgcn_mfma_f32_16x16x32_bf16(a0, b1, acc[0][1], 0, 0, 0);
            acc[1][0] = __builtin_amdgcn_mfma_f32_16x16x32_bf16(a1, b0, acc[1][0], 0, 0, 0);
            acc[1][1] = __builtin_amdgcn_mfma_f32_16x16x32_bf16(a1, b1, acc[1][1], 0, 0, 0);
        }

        if (it == jt) {
#pragma unroll
            for (int r = 0; r < 2; ++r)
#pragma unroll
                for (int c = 0; c < 2; ++c)
#pragma unroll
                    for (int g = 0; g < 4; ++g) {
                        const int jr = wr * 32 + r * 16 + quad * 4 + g;
                        const int ic = wc * 32 + c * 16 + lo;
                        const float pw = (ic >= jr) ? __expf(acc[r][c][g] * SCALE) : 0.f;
                        const float w = pw * rl[r][g];
                        __builtin_nontemporal_store(
                            w, Wb + (size_t)(j0 + jr) * S_ + (size_t)(it * 64 + ic));
                        sP[jr * PP_LD + ic] = f2bf1(w);
                    }
        } else {
#pragma unroll
            for (int r = 0; r < 2; ++r)
#pragma unroll
                for (int c = 0; c < 2; ++c)
#pragma unroll
                    for (int g = 0; g < 4; ++g) {
                        const int jr = wr * 32 + r * 16 + quad * 4 + g;
                        const int ic = wc * 32 + c * 16 + lo;
                        const float w = __expf(acc[r][c][g] * SCALE) * rl[r][g];
                        __builtin_nontemporal_store(
                            w, Wb + (size_t)(j0 + jr) * S_ + (size_t)(it * 64 + ic));
                        sP[jr * PP_LD + ic] = f2bf1(w);
                    }
        }
        __syncthreads();  // sP visible to all waves

        // O += W(64 x 64) * V(64 x 128); wave does 32(j) x 64(d)
        const unsigned short* pP = &sP[(wr * 32 + lo) * PP_LD];
        const unsigned short* pV = &sV[(wc * 64 + lo) * VP_LD];
#pragma unroll
        for (int ks = 0; ks < 2; ++ks) {
            const int ko = ks * 32 + quad * 8;
            short8 a0 = *(const short8*)(pP + ko);
            short8 a1 = *(const short8*)(pP + 16 * PP_LD + ko);
#pragma unroll
            for (int c2 = 0; c2 < 4; ++c2) {
                short8 bv = ldsV8(pV + c2 * 16 * VP_LD + ko);
                acc_o[0][c2] = __builtin_amdgcn_mfma_f32_16x16x32_bf16(a0, bv, acc_o[0][c2], 0, 0, 0);
                acc_o[1][c2] = __builtin_amdgcn_mfma_f32_16x16x32_bf16(a1, bv, acc_o[1][c2], 0, 0, 0);
            }
        }
    }

    // ---- write outputs O (64 x 128 fp32), nontemporal ----
#pragma unroll
    for (int r = 0; r < 2; ++r)
#pragma unroll
        for (int c2 = 0; c2 < 4; ++c2)
#pragma unroll
            for (int g = 0; g < 4; ++g) {
                const int jr = wr * 32 + r * 16 + quad * 4 + g;
                const int dc = wc * 64 + c2 * 16 + lo;
                __builtin_nontemporal_store(acc_o[r][c2][g],
                                            Ob + (size_t)(j0 + jr) * D_ + dc);
            }
}

extern "C" void kernel_launch(void* const* d_in, const int* in_sizes, int n_in,
                              void* d_out, int out_size, void* d_ws, size_t ws_size,
                              hipStream_t stream) {
    const float* Q = (const float*)d_in[0];
    const float* K = (const float*)d_in[1];
    const float* V = (const float*)d_in[2];
    float* out = (float*)d_out;
    (void)in_sizes; (void)n_in; (void)out_size; (void)d_ws; (void)ws_size;
    hipLaunchKernelGGL(attn_kernel, dim3(16 * 32), dim3(256), 0, stream, Q, K, V, out);
}